// Round 14
// baseline (80.879 us; speedup 1.0000x reference)
//
#include <hip/hip_runtime.h>

#define N_TOK 4096
#define L2E 1.44269504088896340736f

typedef short bf16x8 __attribute__((ext_vector_type(8)));
typedef float f32x4 __attribute__((ext_vector_type(4)));
typedef float f32x16 __attribute__((ext_vector_type(16)));
typedef unsigned int u32x4 __attribute__((ext_vector_type(4)));
typedef unsigned short u16x4 __attribute__((ext_vector_type(4)));

static __device__ __forceinline__ unsigned short f2bf(float f) {
    unsigned int u = __builtin_bit_cast(unsigned int, f);
    u += 0x7FFFu + ((u >> 16) & 1u);
    return (unsigned short)(u >> 16);
}
static __device__ __forceinline__ float bf2f(unsigned short v) {
    return __builtin_bit_cast(float, ((unsigned)v) << 16);
}

// --------------------------------------------------------------------------
// Kernel 1: QKV projection. Q,K = [b][n][32] bf16; V = [b][c][n] bf16.
// Q pre-scaled by log2(e) (shift-free exp2 softmax downstream).
// --------------------------------------------------------------------------
__global__ __launch_bounds__(256) void proj_kernel(
    const float* __restrict__ x,
    const float* __restrict__ Wb, const float* __restrict__ bb,
    const float* __restrict__ Wc, const float* __restrict__ bc,
    const float* __restrict__ Wd, const float* __restrict__ bd,
    unsigned short* __restrict__ Qg, unsigned short* __restrict__ Kg,
    unsigned short* __restrict__ VgT)
{
    const int b   = blockIdx.y;
    const int n0  = blockIdx.x * 64;
    const int tid = threadIdx.x;

    __shared__ unsigned short Wl[128 * 72];
    __shared__ unsigned short xT[64 * 72];
    __shared__ float bl[128];

    #pragma unroll
    for (int i = 0; i < 32; ++i) {
        int e = i * 256 + tid;
        int row = e >> 6, c = e & 63;
        float v;
        if (row < 32)      v = Wb[row * 64 + c];
        else if (row < 64) v = Wc[(row - 32) * 64 + c];
        else               v = Wd[(row - 64) * 64 + c];
        Wl[row * 72 + c] = f2bf(v);
    }
    if (tid < 128) {
        float v;
        if (tid < 32)      v = bb[tid];
        else if (tid < 64) v = bc[tid - 32];
        else               v = bd[tid - 64];
        bl[tid] = v;
    }
    #pragma unroll
    for (int i = 0; i < 16; ++i) {
        int e = i * 256 + tid;
        int c = e >> 6, nn = e & 63;
        xT[nn * 72 + c] = f2bf(x[((b * 64 + c) << 12) + n0 + nn]);
    }
    __syncthreads();

    const int w = tid >> 6, l = tid & 63;
    const int lrow = l & 15, lk = (l >> 4) * 8;

    const f32x4 vzero = {0.f, 0.f, 0.f, 0.f};
    f32x4 acc[2][4];
    #pragma unroll
    for (int rt = 0; rt < 2; ++rt)
        #pragma unroll
        for (int ct = 0; ct < 4; ++ct)
            acc[rt][ct] = vzero;

    #pragma unroll
    for (int kb = 0; kb < 2; ++kb) {
        bf16x8 af[2];
        #pragma unroll
        for (int rt = 0; rt < 2; ++rt)
            af[rt] = *(const bf16x8*)&Wl[(w * 32 + rt * 16 + lrow) * 72 + kb * 32 + lk];
        #pragma unroll
        for (int ct = 0; ct < 4; ++ct) {
            bf16x8 bfr = *(const bf16x8*)&xT[(ct * 16 + lrow) * 72 + kb * 32 + lk];
            #pragma unroll
            for (int rt = 0; rt < 2; ++rt)
                acc[rt][ct] = __builtin_amdgcn_mfma_f32_16x16x32_bf16(af[rt], bfr, acc[rt][ct], 0, 0, 0);
        }
    }

    #pragma unroll
    for (int rt = 0; rt < 2; ++rt) {
        const int row0 = w * 32 + rt * 16 + ((l >> 4) << 2);
        #pragma unroll
        for (int ct = 0; ct < 4; ++ct) {
            const int n = n0 + ct * 16 + lrow;
            if (row0 < 64) {
                u16x4 pk;
                #pragma unroll
                for (int r = 0; r < 4; ++r) {
                    float v = acc[rt][ct][r] + bl[row0 + r];
                    if (row0 < 32) v *= L2E;     // Q pre-scale (log2 domain)
                    pk[r] = f2bf(v);
                }
                unsigned short* dst = (row0 < 32)
                    ? Qg + (size_t)(b * N_TOK + n) * 32 + row0
                    : Kg + (size_t)(b * N_TOK + n) * 32 + (row0 - 32);
                *(u16x4*)dst = pk;
            } else {
                #pragma unroll
                for (int r = 0; r < 4; ++r)
                    VgT[((size_t)(b * 64 + row0 - 64 + r) << 12) + n] =
                        f2bf(acc[rt][ct][r] + bl[row0 + r]);
            }
        }
    }
}

// --------------------------------------------------------------------------
// Kernel 2: flash attention, "pack-early" variant.  R9's op order (exp kbg
// 0,1,2,3; PV kbg 0,1,2,3) -> bit-identical output; v13's register diet:
// only ONE 16-reg s block live (S-half is packed to 8 regs of bf16 P right
// after exp2, before QK^T of the other half overwrites s).  Pipe mixing:
// QK^T-half1 (MFMA) overlaps pack-half0 (trans/VALU); PV kbg0,1 (MFMA)
// overlaps pack-half1.  No forced launch bounds (v12 lesson).
// iter t: [stage t+1][prefetch t+2][pack h0][QK^T h1][PV 0,1][pack h1]
// [PV 2,3][barrier][QK^T h0 of t+1].
// --------------------------------------------------------------------------
template <int NHALF>
__global__ __launch_bounds__(256) void attn_kernel(
    const unsigned short* __restrict__ Qg,
    const unsigned short* __restrict__ Kg,
    const unsigned short* __restrict__ VgT,
    const float* __restrict__ x,
    float* __restrict__ outp,              // NHALF==1 only
    unsigned short* __restrict__ Opart,    // [half][b][c][q] bf16
    float* __restrict__ Ppart)             // [half][b][q] f32
{
    const int nwg = 256 * NHALF;
    int i = blockIdx.x;
    int wg = (i & 7) * (nwg >> 3) + (i >> 3);      // XCD-chunked (bijective)
    const int b    = wg / (32 * NHALF);
    const int rem  = wg % (32 * NHALF);
    const int half = (NHALF >= 2) ? (rem >> 5) : 0;
    const int qblk = (NHALF >= 2) ? (rem & 31) : rem;
    const int q0   = qblk * 128;
    const int jbase = half * (N_TOK / NHALF);
    const int NT    = (N_TOK / NHALF) / 64;

    const int tid = threadIdx.x;
    const int w  = tid >> 6, l = tid & 63;
    const int lc = l & 31, hi = l >> 5;

    __shared__ __align__(16) unsigned short Kl[2][64 * 36];   // [j][ch] str 36
    __shared__ __align__(16) unsigned short Vt[2][64 * 68];   // [c][j]  str 68
    __shared__ float den[4][32];

    // Q resident as B-frags: col = q (lc), k = ks*16 + hi*8 + i
    const unsigned short* qp = Qg + (size_t)(b * N_TOK + q0 + w * 32 + lc) * 32 + hi * 8;
    const bf16x8 qf0 = *(const bf16x8*)qp;
    const bf16x8 qf1 = *(const bf16x8*)(qp + 16);

    const int kj = tid >> 2, kseg = (tid & 3) * 8;
    const int vc = tid >> 2, vj   = (tid & 3) * 16;
    const size_t kbase = (size_t)(b * N_TOK + jbase + kj) * 32 + kseg;
    const size_t vbase = ((size_t)(b * 64 + vc) << 12) + jbase + vj;

    u32x4 kreg, vreg0, vreg1;

    // prologue: stage tile 0 into buf 0; prefetch tile 1 into regs
    kreg  = *(const u32x4*)&Kg[kbase];
    vreg0 = *(const u32x4*)&VgT[vbase];
    vreg1 = *(const u32x4*)&VgT[vbase + 8];
    *(u32x4*)&Kl[0][kj * 36 + kseg]   = kreg;
    *(u32x4*)&Vt[0][vc * 68 + vj]     = vreg0;
    *(u32x4*)&Vt[0][vc * 68 + vj + 8] = vreg1;
    if (NT > 1) {
        kreg  = *(const u32x4*)&Kg[kbase + 64 * 32];
        vreg0 = *(const u32x4*)&VgT[vbase + 64];
        vreg1 = *(const u32x4*)&VgT[vbase + 64 + 8];
    }
    __syncthreads();

    const f32x16 z16 = {0.f,0.f,0.f,0.f,0.f,0.f,0.f,0.f,0.f,0.f,0.f,0.f,0.f,0.f,0.f,0.f};
    f32x16 o0 = z16, o1 = z16;
    f32x16 s;                      // single 16-reg S block (both halves)
    float ps0 = 0.f, ps1 = 0.f;
    int cur = 0;

    auto qkt = [&](const unsigned short* Kbuf, int rowoff) {
        __builtin_amdgcn_s_setprio(1);
        const bf16x8 kf0 = *(const bf16x8*)&Kbuf[(rowoff + lc) * 36 + hi * 8];
        const bf16x8 kf1 = *(const bf16x8*)&Kbuf[(rowoff + lc) * 36 + 16 + hi * 8];
        f32x16 r = __builtin_amdgcn_mfma_f32_32x32x16_bf16(kf0, qf0, z16, 0, 0, 0);
        r = __builtin_amdgcn_mfma_f32_32x32x16_bf16(kf1, qf1, r, 0, 0, 0);
        __builtin_amdgcn_s_setprio(0);
        return r;
    };

    // exp2 + cvt_pk + permlane pack of 8 S-values (one kbg) -> u32x4 A-frag
    auto pack8 = [&](int e) {
        float p[8];
        #pragma unroll
        for (int r = 0; r < 8; ++r) {
            p[r] = __builtin_amdgcn_exp2f(s[e + r]);
            if (r & 1) ps1 += p[r]; else ps0 += p[r];
        }
        unsigned A, B, C, D;
        asm("v_cvt_pk_bf16_f32 %0, %1, %2" : "=v"(A) : "v"(p[0]), "v"(p[1]));
        asm("v_cvt_pk_bf16_f32 %0, %1, %2" : "=v"(B) : "v"(p[2]), "v"(p[3]));
        asm("v_cvt_pk_bf16_f32 %0, %1, %2" : "=v"(C) : "v"(p[4]), "v"(p[5]));
        asm("v_cvt_pk_bf16_f32 %0, %1, %2" : "=v"(D) : "v"(p[6]), "v"(p[7]));
        asm("v_permlane32_swap_b32 %0, %1" : "+v"(A), "+v"(C));
        asm("v_permlane32_swap_b32 %0, %1" : "+v"(B), "+v"(D));
        u32x4 out = {A, B, C, D};
        return out;
    };

    auto pv = [&](const u32x4& pw, int kbg) {
        bf16x8 pf = __builtin_bit_cast(bf16x8, pw);
        bf16x8 vf0 = *(const bf16x8*)&Vt[cur][(lc) * 68 + kbg * 16 + hi * 8];
        bf16x8 vf1 = *(const bf16x8*)&Vt[cur][(32 + lc) * 68 + kbg * 16 + hi * 8];
        __builtin_amdgcn_s_setprio(1);
        o0 = __builtin_amdgcn_mfma_f32_32x32x16_bf16(pf, vf0, o0, 0, 0, 0);
        o1 = __builtin_amdgcn_mfma_f32_32x32x16_bf16(pf, vf1, o1, 0, 0, 0);
        __builtin_amdgcn_s_setprio(0);
    };

    // QK^T half0 of tile 0
    s = qkt(&Kl[0][0], 0);

    for (int t = 0; t < NT; ++t) {
        cur = t & 1;

        // stage-write t+1 into buf cur^1 (drains under compute)
        if (t + 1 < NT) {
            *(u32x4*)&Kl[cur ^ 1][kj * 36 + kseg]   = kreg;
            *(u32x4*)&Vt[cur ^ 1][vc * 68 + vj]     = vreg0;
            *(u32x4*)&Vt[cur ^ 1][vc * 68 + vj + 8] = vreg1;
        }
        // prefetch t+2
        if (t + 2 < NT) {
            const int j2 = (t + 2) * 64;
            kreg  = *(const u32x4*)&Kg[kbase + (size_t)j2 * 32];
            vreg0 = *(const u32x4*)&VgT[vbase + j2];
            vreg1 = *(const u32x4*)&VgT[vbase + j2 + 8];
        }

        // pack half0 (kbg 0,1) from s; s then free for half1
        u32x4 pa0 = pack8(0);
        u32x4 pa1 = pack8(8);
        // QK^T half1 (MFMA pipe; overlaps the pack VALU/trans work above)
        s = qkt(&Kl[cur][0], 32);
        // PV of half0 (MFMA) while half1's exp2 (trans) proceeds below
        pv(pa0, 0);
        pv(pa1, 1);
        // pack half1 (kbg 2,3)
        u32x4 pa2 = pack8(0);
        u32x4 pa3 = pack8(8);
        pv(pa2, 2);
        pv(pa3, 3);

        __syncthreads();

        // QK^T half0 of t+1 from freshly staged buf cur^1
        if (t + 1 < NT)
            s = qkt(&Kl[cur ^ 1][0], 0);
    }

    // denominator: lanes (lc,hi=0) and (lc,hi=1) hold disjoint j for q=lc
    float ps = ps0 + ps1;
    float tot = ps + __shfl_xor(ps, 32, 64);

    if (NHALF == 1) {
        if (hi == 0) den[w][lc] = __builtin_amdgcn_rcpf(tot);
        __syncthreads();
        #pragma unroll
        for (int cb = 0; cb < 2; ++cb) {
            const f32x16& ov16 = cb ? o1 : o0;
            const int c = cb * 32 + lc;
            #pragma unroll
            for (int g2 = 0; g2 < 4; ++g2) {
                const int qb = q0 + w * 32 + g2 * 8 + hi * 4;
                f32x4 rinv = *(const f32x4*)&den[w][g2 * 8 + hi * 4];
                const size_t idx = (size_t)(b * 64 + c) * N_TOK + qb;
                f32x4 xv = *(const f32x4*)&x[idx];
                f32x4 ov;
                #pragma unroll
                for (int r = 0; r < 4; ++r)
                    ov[r] = ov16[g2 * 4 + r] * rinv[r] + xv[r];
                *(f32x4*)&outp[idx] = ov;
            }
        }
    } else {
        #pragma unroll
        for (int cb = 0; cb < 2; ++cb) {
            const f32x16& ov16 = cb ? o1 : o0;
            unsigned short* obase =
                Opart + ((size_t)((half * 8 + b) * 64 + cb * 32 + lc) << 12);
            #pragma unroll
            for (int g2 = 0; g2 < 4; ++g2) {
                const int qb = q0 + w * 32 + g2 * 8 + hi * 4;
                u16x4 pk;
                #pragma unroll
                for (int r = 0; r < 4; ++r) pk[r] = f2bf(ov16[g2 * 4 + r]);
                *(u16x4*)(obase + qb) = pk;
            }
        }
        if (hi == 0)
            Ppart[((size_t)(half * 8 + b) << 12) + q0 + w * 32 + lc] = tot;
    }
}

// --------------------------------------------------------------------------
// Kernel 3: combine NHALF partials: out = (ΣO_h)/(Σp_h) + x.
// --------------------------------------------------------------------------
template <int NHALF>
__global__ __launch_bounds__(256) void combine_kernel(
    const unsigned short* __restrict__ Opart, const float* __restrict__ Ppart,
    const float* __restrict__ x, float* __restrict__ outp)
{
    const int i = blockIdx.x * 256 + threadIdx.x;     // f32x4 index
    const int q  = (i & 1023) << 2;
    const int bc = i >> 10;                            // b*64+c
    const int b  = bc >> 6;
    const size_t obase = ((size_t)bc << 12) + q;

    f32x4 osum = {0.f, 0.f, 0.f, 0.f};
    f32x4 psum = {0.f, 0.f, 0.f, 0.f};
    #pragma unroll
    for (int h = 0; h < NHALF; ++h) {
        u16x4 oh = *(const u16x4*)&Opart[(((size_t)(h * 512 + bc)) << 12) + q];
        f32x4 ph = *(const f32x4*)&Ppart[(((size_t)(h * 8 + b)) << 12) + q];
        #pragma unroll
        for (int r = 0; r < 4; ++r) { osum[r] += bf2f(oh[r]); psum[r] += ph[r]; }
    }
    f32x4 xv = *(const f32x4*)&x[obase];
    f32x4 ov;
    #pragma unroll
    for (int r = 0; r < 4; ++r)
        ov[r] = osum[r] * __builtin_amdgcn_rcpf(psum[r]) + xv[r];
    *(f32x4*)&outp[obase] = ov;
}

extern "C" void kernel_launch(void* const* d_in, const int* in_sizes, int n_in,
                              void* d_out, int out_size, void* d_ws, size_t ws_size,
                              hipStream_t stream) {
    const float* x  = (const float*)d_in[0];
    const float* Wb = (const float*)d_in[1];
    const float* bb = (const float*)d_in[2];
    const float* Wc = (const float*)d_in[3];
    const float* bc = (const float*)d_in[4];
    const float* Wd = (const float*)d_in[5];
    const float* bd = (const float*)d_in[6];
    float* out = (float*)d_out;

    // ws: QKV bf16 0..8MB | Opart bf16 8..24MB | Ppart f32 24..24.5MB
    unsigned short* Qg  = (unsigned short*)d_ws;
    unsigned short* Kg  = Qg + (size_t)8 * N_TOK * 32;
    unsigned short* VgT = Kg + (size_t)8 * N_TOK * 32;
    unsigned short* Opart = (unsigned short*)((char*)d_ws + (size_t)8 * 1024 * 1024);
    float* Ppart = (float*)((char*)d_ws + (size_t)24 * 1024 * 1024);

    proj_kernel<<<dim3(64, 8), 256, 0, stream>>>(x, Wb, bb, Wc, bc, Wd, bd, Qg, Kg, VgT);

    if (ws_size >= (size_t)25 * 1024 * 1024) {
        attn_kernel<4><<<1024, 256, 0, stream>>>(Qg, Kg, VgT, x, out, Opart, Ppart);
        combine_kernel<4><<<2048, 256, 0, stream>>>(Opart, Ppart, x, out);
    } else {
        attn_kernel<1><<<256, 256, 0, stream>>>(Qg, Kg, VgT, x, out, nullptr, nullptr);
    }
}

// Round 15
// 57.548 us; speedup vs baseline: 1.4054x; 1.4054x over previous
//
#include <hip/hip_runtime.h>

#define N_TOK 4096
#define L2E 1.44269504088896340736f

typedef short bf16x8 __attribute__((ext_vector_type(8)));
typedef float f32x4 __attribute__((ext_vector_type(4)));
typedef float f32x16 __attribute__((ext_vector_type(16)));
typedef unsigned int u32x4 __attribute__((ext_vector_type(4)));
typedef unsigned short u16x4 __attribute__((ext_vector_type(4)));

static __device__ __forceinline__ unsigned short f2bf(float f) {
    unsigned int u = __builtin_bit_cast(unsigned int, f);
    u += 0x7FFFu + ((u >> 16) & 1u);
    return (unsigned short)(u >> 16);
}
static __device__ __forceinline__ float bf2f(unsigned short v) {
    return __builtin_bit_cast(float, ((unsigned)v) << 16);
}

// --------------------------------------------------------------------------
// Kernel 1: QKV projection. Q,K = [b][n][32] bf16; V = [b][c][n] bf16.
// Q pre-scaled by log2(e) (shift-free exp2 softmax downstream).
// --------------------------------------------------------------------------
__global__ __launch_bounds__(256) void proj_kernel(
    const float* __restrict__ x,
    const float* __restrict__ Wb, const float* __restrict__ bb,
    const float* __restrict__ Wc, const float* __restrict__ bc,
    const float* __restrict__ Wd, const float* __restrict__ bd,
    unsigned short* __restrict__ Qg, unsigned short* __restrict__ Kg,
    unsigned short* __restrict__ VgT)
{
    const int b   = blockIdx.y;
    const int n0  = blockIdx.x * 64;
    const int tid = threadIdx.x;

    __shared__ unsigned short Wl[128 * 72];
    __shared__ unsigned short xT[64 * 72];
    __shared__ float bl[128];

    #pragma unroll
    for (int i = 0; i < 32; ++i) {
        int e = i * 256 + tid;
        int row = e >> 6, c = e & 63;
        float v;
        if (row < 32)      v = Wb[row * 64 + c];
        else if (row < 64) v = Wc[(row - 32) * 64 + c];
        else               v = Wd[(row - 64) * 64 + c];
        Wl[row * 72 + c] = f2bf(v);
    }
    if (tid < 128) {
        float v;
        if (tid < 32)      v = bb[tid];
        else if (tid < 64) v = bc[tid - 32];
        else               v = bd[tid - 64];
        bl[tid] = v;
    }
    #pragma unroll
    for (int i = 0; i < 16; ++i) {
        int e = i * 256 + tid;
        int c = e >> 6, nn = e & 63;
        xT[nn * 72 + c] = f2bf(x[((b * 64 + c) << 12) + n0 + nn]);
    }
    __syncthreads();

    const int w = tid >> 6, l = tid & 63;
    const int lrow = l & 15, lk = (l >> 4) * 8;

    const f32x4 vzero = {0.f, 0.f, 0.f, 0.f};
    f32x4 acc[2][4];
    #pragma unroll
    for (int rt = 0; rt < 2; ++rt)
        #pragma unroll
        for (int ct = 0; ct < 4; ++ct)
            acc[rt][ct] = vzero;

    #pragma unroll
    for (int kb = 0; kb < 2; ++kb) {
        bf16x8 af[2];
        #pragma unroll
        for (int rt = 0; rt < 2; ++rt)
            af[rt] = *(const bf16x8*)&Wl[(w * 32 + rt * 16 + lrow) * 72 + kb * 32 + lk];
        #pragma unroll
        for (int ct = 0; ct < 4; ++ct) {
            bf16x8 bfr = *(const bf16x8*)&xT[(ct * 16 + lrow) * 72 + kb * 32 + lk];
            #pragma unroll
            for (int rt = 0; rt < 2; ++rt)
                acc[rt][ct] = __builtin_amdgcn_mfma_f32_16x16x32_bf16(af[rt], bfr, acc[rt][ct], 0, 0, 0);
        }
    }

    #pragma unroll
    for (int rt = 0; rt < 2; ++rt) {
        const int row0 = w * 32 + rt * 16 + ((l >> 4) << 2);
        #pragma unroll
        for (int ct = 0; ct < 4; ++ct) {
            const int n = n0 + ct * 16 + lrow;
            if (row0 < 64) {
                u16x4 pk;
                #pragma unroll
                for (int r = 0; r < 4; ++r) {
                    float v = acc[rt][ct][r] + bl[row0 + r];
                    if (row0 < 32) v *= L2E;     // Q pre-scale (log2 domain)
                    pk[r] = f2bf(v);
                }
                unsigned short* dst = (row0 < 32)
                    ? Qg + (size_t)(b * N_TOK + n) * 32 + row0
                    : Kg + (size_t)(b * N_TOK + n) * 32 + (row0 - 32);
                *(u16x4*)dst = pk;
            } else {
                #pragma unroll
                for (int r = 0; r < 4; ++r)
                    VgT[((size_t)(b * 64 + row0 - 64 + r) << 12) + n] =
                        f2bf(acc[rt][ct][r] + bl[row0 + r]);
            }
        }
    }
}

// --------------------------------------------------------------------------
// Kernel 2: flash attention (R9 exact structure, best-known).  NHALF-way KV
// split, 256 thr = 4 waves x 32q = 128 q/block.  Cross-barrier software
// pipeline: iter t = [stage-write t+1 -> buf cur^1][prefetch t+2][per-kb:
// 8 exp2 + cvt/permlane pack -> 2 PV MFMA, from buf cur][barrier][QK^T(t+1)
// from buf cur^1].  One barrier/tile; MFMA on both sides of barrier.
// Partials: Opart bf16 [half][b][c][q], Ppart f32 [half][b][q].
// --------------------------------------------------------------------------
template <int NHALF>
__global__ __launch_bounds__(256) void attn_kernel(
    const unsigned short* __restrict__ Qg,
    const unsigned short* __restrict__ Kg,
    const unsigned short* __restrict__ VgT,
    const float* __restrict__ x,
    float* __restrict__ outp,              // NHALF==1 only
    unsigned short* __restrict__ Opart,    // [half][b][c][q] bf16
    float* __restrict__ Ppart)             // [half][b][q] f32
{
    const int nwg = 256 * NHALF;
    int i = blockIdx.x;
    int wg = (i & 7) * (nwg >> 3) + (i >> 3);      // XCD-chunked (bijective)
    const int b    = wg / (32 * NHALF);
    const int rem  = wg % (32 * NHALF);
    const int half = (NHALF >= 2) ? (rem >> 5) : 0;
    const int qblk = (NHALF >= 2) ? (rem & 31) : rem;
    const int q0   = qblk * 128;
    const int jbase = half * (N_TOK / NHALF);
    const int NT    = (N_TOK / NHALF) / 64;

    const int tid = threadIdx.x;
    const int w  = tid >> 6, l = tid & 63;
    const int lc = l & 31, hi = l >> 5;

    __shared__ __align__(16) unsigned short Kl[2][64 * 36];   // [j][ch] str 36
    __shared__ __align__(16) unsigned short Vt[2][64 * 68];   // [c][j]  str 68
    __shared__ float den[4][32];

    // Q resident as B-frags: col = q (lc), k = ks*16 + hi*8 + i
    const unsigned short* qp = Qg + (size_t)(b * N_TOK + q0 + w * 32 + lc) * 32 + hi * 8;
    const bf16x8 qf0 = *(const bf16x8*)qp;
    const bf16x8 qf1 = *(const bf16x8*)(qp + 16);

    const int kj = tid >> 2, kseg = (tid & 3) * 8;
    const int vc = tid >> 2, vj   = (tid & 3) * 16;
    const size_t kbase = (size_t)(b * N_TOK + jbase + kj) * 32 + kseg;
    const size_t vbase = ((size_t)(b * 64 + vc) << 12) + jbase + vj;

    u32x4 kreg, vreg0, vreg1;

    // prologue: stage tile 0 into buf 0; prefetch tile 1 into regs
    kreg  = *(const u32x4*)&Kg[kbase];
    vreg0 = *(const u32x4*)&VgT[vbase];
    vreg1 = *(const u32x4*)&VgT[vbase + 8];
    *(u32x4*)&Kl[0][kj * 36 + kseg]   = kreg;
    *(u32x4*)&Vt[0][vc * 68 + vj]     = vreg0;
    *(u32x4*)&Vt[0][vc * 68 + vj + 8] = vreg1;
    if (NT > 1) {
        kreg  = *(const u32x4*)&Kg[kbase + 64 * 32];
        vreg0 = *(const u32x4*)&VgT[vbase + 64];
        vreg1 = *(const u32x4*)&VgT[vbase + 64 + 8];
    }
    __syncthreads();

    const f32x16 z16 = {0.f,0.f,0.f,0.f,0.f,0.f,0.f,0.f,0.f,0.f,0.f,0.f,0.f,0.f,0.f,0.f};
    f32x16 o0 = z16, o1 = z16;
    f32x16 s0, s1;
    float ps0 = 0.f, ps1 = 0.f;

    // QK^T(t0) from buf 0
    {
        __builtin_amdgcn_s_setprio(1);
        bf16x8 a00 = *(const bf16x8*)&Kl[0][(lc) * 36 + hi * 8];
        bf16x8 a01 = *(const bf16x8*)&Kl[0][(lc) * 36 + 16 + hi * 8];
        bf16x8 a10 = *(const bf16x8*)&Kl[0][(32 + lc) * 36 + hi * 8];
        bf16x8 a11 = *(const bf16x8*)&Kl[0][(32 + lc) * 36 + 16 + hi * 8];
        s0 = __builtin_amdgcn_mfma_f32_32x32x16_bf16(a00, qf0, z16, 0, 0, 0);
        s0 = __builtin_amdgcn_mfma_f32_32x32x16_bf16(a01, qf1, s0, 0, 0, 0);
        s1 = __builtin_amdgcn_mfma_f32_32x32x16_bf16(a10, qf0, z16, 0, 0, 0);
        s1 = __builtin_amdgcn_mfma_f32_32x32x16_bf16(a11, qf1, s1, 0, 0, 0);
        __builtin_amdgcn_s_setprio(0);
    }

    for (int t = 0; t < NT; ++t) {
        const int cur = t & 1;

        // stage-write t+1 into buf cur^1 (drains under compute)
        if (t + 1 < NT) {
            *(u32x4*)&Kl[cur ^ 1][kj * 36 + kseg]   = kreg;
            *(u32x4*)&Vt[cur ^ 1][vc * 68 + vj]     = vreg0;
            *(u32x4*)&Vt[cur ^ 1][vc * 68 + vj + 8] = vreg1;
        }
        // prefetch t+2
        if (t + 2 < NT) {
            const int j2 = (t + 2) * 64;
            kreg  = *(const u32x4*)&Kg[kbase + (size_t)j2 * 32];
            vreg0 = *(const u32x4*)&VgT[vbase + j2];
            vreg1 = *(const u32x4*)&VgT[vbase + j2 + 8];
        }

        // per-kb interleave: {8 exp2 + pack} -> {2 PV MFMA}
        #pragma unroll
        for (int kb = 0; kb < 4; ++kb) {
            const f32x16& sv = (kb >> 1) ? s1 : s0;
            const int e = (kb & 1) * 8;
            float p[8];
            #pragma unroll
            for (int r = 0; r < 8; ++r) {
                p[r] = __builtin_amdgcn_exp2f(sv[e + r]);
                if (r & 1) ps1 += p[r]; else ps0 += p[r];
            }
            unsigned A, B, C, D;
            asm("v_cvt_pk_bf16_f32 %0, %1, %2" : "=v"(A) : "v"(p[0]), "v"(p[1]));
            asm("v_cvt_pk_bf16_f32 %0, %1, %2" : "=v"(B) : "v"(p[2]), "v"(p[3]));
            asm("v_cvt_pk_bf16_f32 %0, %1, %2" : "=v"(C) : "v"(p[4]), "v"(p[5]));
            asm("v_cvt_pk_bf16_f32 %0, %1, %2" : "=v"(D) : "v"(p[6]), "v"(p[7]));
            asm("v_permlane32_swap_b32 %0, %1" : "+v"(A), "+v"(C));
            asm("v_permlane32_swap_b32 %0, %1" : "+v"(B), "+v"(D));
            u32x4 pw = {A, B, C, D};
            bf16x8 pf = __builtin_bit_cast(bf16x8, pw);
            bf16x8 vf0 = *(const bf16x8*)&Vt[cur][(lc) * 68 + kb * 16 + hi * 8];
            bf16x8 vf1 = *(const bf16x8*)&Vt[cur][(32 + lc) * 68 + kb * 16 + hi * 8];
            __builtin_amdgcn_s_setprio(1);
            o0 = __builtin_amdgcn_mfma_f32_32x32x16_bf16(pf, vf0, o0, 0, 0, 0);
            o1 = __builtin_amdgcn_mfma_f32_32x32x16_bf16(pf, vf1, o1, 0, 0, 0);
            __builtin_amdgcn_s_setprio(0);
        }

        __syncthreads();

        // QK^T(t+1) from freshly staged buf cur^1
        if (t + 1 < NT) {
            const int nxt = cur ^ 1;
            __builtin_amdgcn_s_setprio(1);
            bf16x8 a00 = *(const bf16x8*)&Kl[nxt][(lc) * 36 + hi * 8];
            bf16x8 a01 = *(const bf16x8*)&Kl[nxt][(lc) * 36 + 16 + hi * 8];
            bf16x8 a10 = *(const bf16x8*)&Kl[nxt][(32 + lc) * 36 + hi * 8];
            bf16x8 a11 = *(const bf16x8*)&Kl[nxt][(32 + lc) * 36 + 16 + hi * 8];
            s0 = __builtin_amdgcn_mfma_f32_32x32x16_bf16(a00, qf0, z16, 0, 0, 0);
            s0 = __builtin_amdgcn_mfma_f32_32x32x16_bf16(a01, qf1, s0, 0, 0, 0);
            s1 = __builtin_amdgcn_mfma_f32_32x32x16_bf16(a10, qf0, z16, 0, 0, 0);
            s1 = __builtin_amdgcn_mfma_f32_32x32x16_bf16(a11, qf1, s1, 0, 0, 0);
            __builtin_amdgcn_s_setprio(0);
        }
    }

    // denominator: lanes (lc,hi=0) and (lc,hi=1) hold disjoint j for q=lc
    float ps = ps0 + ps1;
    float tot = ps + __shfl_xor(ps, 32, 64);

    if (NHALF == 1) {
        if (hi == 0) den[w][lc] = __builtin_amdgcn_rcpf(tot);
        __syncthreads();
        #pragma unroll
        for (int cb = 0; cb < 2; ++cb) {
            const f32x16& ov16 = cb ? o1 : o0;
            const int c = cb * 32 + lc;
            #pragma unroll
            for (int g2 = 0; g2 < 4; ++g2) {
                const int qb = q0 + w * 32 + g2 * 8 + hi * 4;
                f32x4 rinv = *(const f32x4*)&den[w][g2 * 8 + hi * 4];
                const size_t idx = (size_t)(b * 64 + c) * N_TOK + qb;
                f32x4 xv = *(const f32x4*)&x[idx];
                f32x4 ov;
                #pragma unroll
                for (int r = 0; r < 4; ++r)
                    ov[r] = ov16[g2 * 4 + r] * rinv[r] + xv[r];
                *(f32x4*)&outp[idx] = ov;
            }
        }
    } else {
        #pragma unroll
        for (int cb = 0; cb < 2; ++cb) {
            const f32x16& ov16 = cb ? o1 : o0;
            unsigned short* obase =
                Opart + ((size_t)((half * 8 + b) * 64 + cb * 32 + lc) << 12);
            #pragma unroll
            for (int g2 = 0; g2 < 4; ++g2) {
                const int qb = q0 + w * 32 + g2 * 8 + hi * 4;
                u16x4 pk;
                #pragma unroll
                for (int r = 0; r < 4; ++r) pk[r] = f2bf(ov16[g2 * 4 + r]);
                *(u16x4*)(obase + qb) = pk;
            }
        }
        if (hi == 0)
            Ppart[((size_t)(half * 8 + b) << 12) + q0 + w * 32 + lc] = tot;
    }
}

// --------------------------------------------------------------------------
// Kernel 3: combine NHALF partials: out = (ΣO_h)/(Σp_h) + x.
// --------------------------------------------------------------------------
template <int NHALF>
__global__ __launch_bounds__(256) void combine_kernel(
    const unsigned short* __restrict__ Opart, const float* __restrict__ Ppart,
    const float* __restrict__ x, float* __restrict__ outp)
{
    const int i = blockIdx.x * 256 + threadIdx.x;     // f32x4 index
    const int q  = (i & 1023) << 2;
    const int bc = i >> 10;                            // b*64+c
    const int b  = bc >> 6;
    const size_t obase = ((size_t)bc << 12) + q;

    f32x4 osum = {0.f, 0.f, 0.f, 0.f};
    f32x4 psum = {0.f, 0.f, 0.f, 0.f};
    #pragma unroll
    for (int h = 0; h < NHALF; ++h) {
        u16x4 oh = *(const u16x4*)&Opart[(((size_t)(h * 512 + bc)) << 12) + q];
        f32x4 ph = *(const f32x4*)&Ppart[(((size_t)(h * 8 + b)) << 12) + q];
        #pragma unroll
        for (int r = 0; r < 4; ++r) { osum[r] += bf2f(oh[r]); psum[r] += ph[r]; }
    }
    f32x4 xv = *(const f32x4*)&x[obase];
    f32x4 ov;
    #pragma unroll
    for (int r = 0; r < 4; ++r)
        ov[r] = osum[r] * __builtin_amdgcn_rcpf(psum[r]) + xv[r];
    *(f32x4*)&outp[obase] = ov;
}

extern "C" void kernel_launch(void* const* d_in, const int* in_sizes, int n_in,
                              void* d_out, int out_size, void* d_ws, size_t ws_size,
                              hipStream_t stream) {
    const float* x  = (const float*)d_in[0];
    const float* Wb = (const float*)d_in[1];
    const float* bb = (const float*)d_in[2];
    const float* Wc = (const float*)d_in[3];
    const float* bc = (const float*)d_in[4];
    const float* Wd = (const float*)d_in[5];
    const float* bd = (const float*)d_in[6];
    float* out = (float*)d_out;

    // ws: QKV bf16 0..8MB | Opart bf16 8..24MB | Ppart f32 24..24.5MB
    unsigned short* Qg  = (unsigned short*)d_ws;
    unsigned short* Kg  = Qg + (size_t)8 * N_TOK * 32;
    unsigned short* VgT = Kg + (size_t)8 * N_TOK * 32;
    unsigned short* Opart = (unsigned short*)((char*)d_ws + (size_t)8 * 1024 * 1024);
    float* Ppart = (float*)((char*)d_ws + (size_t)24 * 1024 * 1024);

    proj_kernel<<<dim3(64, 8), 256, 0, stream>>>(x, Wb, bb, Wc, bc, Wd, bd, Qg, Kg, VgT);

    if (ws_size >= (size_t)25 * 1024 * 1024) {
        attn_kernel<2><<<512, 256, 0, stream>>>(Qg, Kg, VgT, x, out, Opart, Ppart);
        combine_kernel<2><<<2048, 256, 0, stream>>>(Opart, Ppart, x, out);
    } else {
        attn_kernel<1><<<256, 256, 0, stream>>>(Qg, Kg, VgT, x, out, nullptr, nullptr);
    }
}